// Round 6
// baseline (81.412 us; speedup 1.0000x reference)
//
#include <hip/hip_runtime.h>
#include <math.h>

#define B_ 4
#define H_ 12
#define N_ 1025
#define D_ 64
#define HID_ 32
#define TBL_ 3969            // (2*32-1)^2
#define NQT 17               // 64-row tiles in both q and k
#define NBLK (B_ * H_ * NQT) // 816, divisible by 8
#define LOG2E 1.44269504f
#define THR_ 12.0f           // defer-max threshold (log2 domain); p <= 2^12 fits f16

typedef _Float16 half8 __attribute__((ext_vector_type(8)));
typedef __fp16 fp16x2 __attribute__((ext_vector_type(2)));
typedef float f32x4 __attribute__((ext_vector_type(4)));

#if defined(__has_builtin)
#if __has_builtin(__builtin_amdgcn_exp2f)
#define EX2 __builtin_amdgcn_exp2f
#else
#define EX2 exp2f
#endif
#else
#define EX2 exp2f
#endif

// ws layout (bytes):
//   btT @ 0        : 12*3969*4 = 190512
//   akT @ 190512   : 48*1088*4 = 208896   (also the finite overrun pad for btT)
//   Kf  @ 399408   : 48*17*4096*2 = 6684672
//   Vf  @ 7084080  : 6684672              (end 13768752)
#define BTT_OFF 0
#define AKT_OFF 190512
#define KF_OFF 399408
#define VF_OFF 7084080

// ---------------- prep: K/V -> f16 fragment-order tiles (V via LDS transpose),
// akT = sigmoid(gamma)*log2e*mu_k, btT = MLP bias table (per-head transposed)
__global__ __launch_bounds__(256) void prep(
    const float* __restrict__ K, const float* __restrict__ V,
    const float* __restrict__ MU, const float* __restrict__ GAMMA,
    const float* __restrict__ rel, const float* __restrict__ w1,
    const float* __restrict__ b1, const float* __restrict__ w2,
    _Float16* __restrict__ Kf, _Float16* __restrict__ Vf,
    float* __restrict__ akT, float* __restrict__ btT) {
    const int bid = blockIdx.x;
    const int tid = threadIdx.x;
    if (bid < NBLK) {
        __shared__ float Vls[64 * 65];  // [d][k], pad 65 (2-way banks max)
        const int bh = bid / NQT, kt = bid % NQT;
        const size_t base = (size_t)bh * (N_ * D_);
        const int k0 = kt * 64;
        // V rows: coalesced global read -> transposed LDS scatter
#pragma unroll
        for (int it = 0; it < 4; ++it) {
            const int idx = it * 256 + tid;
            const int kr = idx >> 4, c4 = (idx & 15) << 2;
            const int kg = k0 + kr;
            float4 v4 = make_float4(0, 0, 0, 0);
            if (kg < N_) v4 = *(const float4*)(V + base + (size_t)kg * D_ + c4);
            Vls[(c4 + 0) * 65 + kr] = v4.x;
            Vls[(c4 + 1) * 65 + kr] = v4.y;
            Vls[(c4 + 2) * 65 + kr] = v4.z;
            Vls[(c4 + 3) * 65 + kr] = v4.w;
        }
        __syncthreads();
        const int lane = tid & 63, lq = lane & 15, g = lane >> 4;
        const int fbh = tid >> 6;
        const size_t tb = (size_t)(bh * NQT + kt) * 4096;
#pragma unroll
        for (int x = 0; x < 2; ++x) {
            const int fb = fbh + x * 4;
            {   // V fragment fb = kh*4+dg from LDS
                const int kh = fb >> 2, dg = fb & 3;
                const float* vp = &Vls[(dg * 16 + lq) * 65 + kh * 32 + g * 8];
                half8 v8;
#pragma unroll
                for (int j = 0; j < 8; ++j) v8[j] = (_Float16)vp[j];
                *(half8*)&Vf[tb + fb * 512 + lane * 8] = v8;
            }
            {   // K fragment fb = kg2*2+dh, direct
                const int row = k0 + (fb >> 1) * 16 + lq;
                const int col = (fb & 1) * 32 + g * 8;
                half8 k8;
                if (row < N_) {
                    const float4* p = (const float4*)(K + base + (size_t)row * D_ + col);
                    float4 a = p[0], b = p[1];
                    k8[0] = (_Float16)a.x; k8[1] = (_Float16)a.y;
                    k8[2] = (_Float16)a.z; k8[3] = (_Float16)a.w;
                    k8[4] = (_Float16)b.x; k8[5] = (_Float16)b.y;
                    k8[6] = (_Float16)b.z; k8[7] = (_Float16)b.w;
                } else {
#pragma unroll
                    for (int j = 0; j < 8; ++j) k8[j] = (_Float16)0.f;
                }
                *(half8*)&Kf[tb + fb * 512 + lane * 8] = k8;
            }
        }
        if (tid < 64) {
            const int kk = k0 + tid;
            const int h = bh % H_;
            const float sgl = LOG2E / (1.f + __expf(-GAMMA[h]));
            float a = 0.f;
            if (kk >= 1 && kk < N_) a = sgl * MU[((size_t)bh * 2 + 1) * N_ + kk];
            akT[bh * 1088 + kk] = a;
        }
    } else {
        const int i = (bid - NBLK) * 256 + tid;
        if (i < TBL_) {
            const float x0 = rel[2 * i + 0], x1 = rel[2 * i + 1];
            float acc[H_];
#pragma unroll
            for (int h = 0; h < H_; ++h) acc[h] = 0.f;
#pragma unroll
            for (int j = 0; j < HID_; ++j) {
                float t = fmaf(x0, w1[j], fmaf(x1, w1[HID_ + j], b1[j]));
                float gl = 0.5f * t * (1.f + erff(t * 0.7071067811865475f));  // exact gelu
#pragma unroll
                for (int h = 0; h < H_; ++h) acc[h] = fmaf(gl, w2[j * H_ + h], acc[h]);
            }
#pragma unroll
            for (int h = 0; h < H_; ++h) btT[h * TBL_ + i] = acc[h];
        }
    }
}

// ---------------- fused flash attention, f16 MFMA, register-resident fragments,
// ZERO barriers: every wave runs free; K ping-pong prefetch, V loaded per tile.
__global__ __launch_bounds__(256, 2) void flex_attn(
    const float* __restrict__ Q, const _Float16* __restrict__ Kf,
    const _Float16* __restrict__ Vf, const float* __restrict__ MU,
    const float* __restrict__ GAMMA, const char* __restrict__ btb,  // ws - 2048
    const float* __restrict__ akT, float* __restrict__ OUT) {
    __shared__ __align__(16) _Float16 Pl[4][1024];  // per-wave P tile, XOR-swizzled

    const int bid = blockIdx.x;
    const int swz0 = (bid & 7) * (NBLK / 8) + (bid >> 3);  // bijective XCD swizzle
    const int bh = swz0 / NQT;
    const int qt = swz0 % NQT;
    const int h = bh % H_;
    const int tid = threadIdx.x;
    const int w = tid >> 6;
    const int lane = tid & 63;
    const int lq = lane & 15;
    const int g = lane >> 4;

    const size_t base = (size_t)bh * (N_ * D_);
    const float sg = LOG2E / (1.f + __expf(-GAMMA[h]));

    const int qrow = qt * 64 + w * 16 + lq;
    const bool qv = qrow < N_;

    // Q fragment (B-operand of swapped QK^T), scale = log2e/sqrt(64)
    half8 qf[2];
#pragma unroll
    for (int dh = 0; dh < 2; ++dh) {
        float4 t0 = make_float4(0, 0, 0, 0), t1 = t0;
        if (qv) {
            const float4* qp = (const float4*)(Q + base + (size_t)qrow * D_ + dh * 32 + g * 8);
            t0 = qp[0]; t1 = qp[1];
        }
        const float qs = 0.125f * LOG2E;
        half8 q8;
        q8[0] = (_Float16)(t0.x * qs); q8[1] = (_Float16)(t0.y * qs);
        q8[2] = (_Float16)(t0.z * qs); q8[3] = (_Float16)(t0.w * qs);
        q8[4] = (_Float16)(t1.x * qs); q8[5] = (_Float16)(t1.y * qs);
        q8[6] = (_Float16)(t1.z * qs); q8[7] = (_Float16)(t1.w * qs);
        qf[dh] = q8;
    }

    const bool qb = qv && (qrow >= 1);
    const float qbf = qb ? 1.f : 0.f;
    float aq = 0.f;
    int cq = 0;
    if (qb) {
        const int pq = qrow - 1;
        cq = (pq >> 5) * 63 + (pq & 31);
        aq = sg * MU[(size_t)bh * 2 * N_ + qrow];  // sg*log2e*mu_q
    }
    // bias gather byte offsets vs btb = ws-2048: off = (h*TBL + cq + 1984 - ck)*4 + 2048
    // per-tile recurrence: ck += 126 exactly  =>  off -= 504
    int boffs[16];
#pragma unroll
    for (int kg = 0; kg < 4; ++kg) {
#pragma unroll
        for (int r = 0; r < 4; ++r) {
            const int pk = kg * 16 + g * 4 + r - 1;       // tile 0
            const int ck = (pk >> 5) * 63 + (pk & 31);    // arith shift: ck(-1) = -32
            boffs[kg * 4 + r] = (h * TBL_ + cq + 1984 - ck) * 4 + 2048;
        }
    }
    const float* akb = akT + bh * 1088;
    const _Float16* kfb = Kf + (size_t)bh * NQT * 4096 + lane * 8;
    const _Float16* vfb = Vf + (size_t)bh * NQT * 4096 + lane * 8;

    f32x4 o[4];
    const f32x4 zz = {0.f, 0.f, 0.f, 0.f};
#pragma unroll
    for (int dg = 0; dg < 4; ++dg) o[dg] = zz;
    float m = 0.f, lsum = 0.f;

    const int pswz = (lq & 7) << 4;
    char* plw = (char*)&Pl[w][0];

    half8 kA[8], kB[8], vv[8];
    // prologue: K fragments of tile 0 into kA
#pragma unroll
    for (int f = 0; f < 8; ++f) kA[f] = *(const half8*)(kfb + f * 512);

#define TILE_BODY(KC, KN, TT, DO_PRE)                                                   \
    {                                                                                   \
        const int t_ = (TT);                                                            \
        /* V fragments of this tile (consumed at PV, hidden under QK+softmax) */        \
        {                                                                               \
            const _Float16* vp_ = vfb + (size_t)t_ * 4096;                              \
            _Pragma("unroll") for (int f = 0; f < 8; ++f)                               \
                vv[f] = *(const half8*)(vp_ + f * 512);                                 \
        }                                                                               \
        /* bias gathers (bare saddr loads; clamp floor only bites the masked corner) */ \
        float bt16[16];                                                                 \
        _Pragma("unroll") for (int i = 0; i < 16; ++i) {                                \
            int off = boffs[i];                                                         \
            off = off < 2048 ? 2048 : off;                                              \
            bt16[i] = *(const float*)(btb + (uint32_t)off);                             \
            boffs[i] -= 504;                                                            \
        }                                                                               \
        f32x4 akq[4];                                                                   \
        _Pragma("unroll") for (int kg = 0; kg < 4; ++kg)                                \
            akq[kg] = *(const f32x4*)(akb + t_ * 64 + kg * 16 + g * 4);                 \
        /* QK^T (swapped): C[k][q] */                                                   \
        f32x4 sa[4];                                                                    \
        _Pragma("unroll") for (int kg = 0; kg < 4; ++kg) {                              \
            f32x4 z = zz;                                                               \
            z = __builtin_amdgcn_mfma_f32_16x16x32_f16(KC[2 * kg + 0], qf[0], z, 0, 0, 0); \
            z = __builtin_amdgcn_mfma_f32_16x16x32_f16(KC[2 * kg + 1], qf[1], z, 0, 0, 0); \
            sa[kg] = z;                                                                 \
        }                                                                               \
        /* prefetch next tile's K fragments */                                          \
        if (DO_PRE) {                                                                   \
            const _Float16* kp_ = kfb + (size_t)(t_ + 1) * 4096;                        \
            _Pragma("unroll") for (int f = 0; f < 8; ++f)                               \
                KN[f] = *(const half8*)(kp_ + f * 512);                                 \
        }                                                                               \
        /* scores (log2 domain): s = sa + (qbf*ak + aq)*bt */                           \
        if (t_ == 0 && g == 0) bt16[0] = 0.f; /* k=0 column has no bias */              \
        float s[16];                                                                    \
        _Pragma("unroll") for (int kg = 0; kg < 4; ++kg) {                              \
            _Pragma("unroll") for (int r = 0; r < 4; ++r) {                             \
                const int i = kg * 4 + r;                                               \
                s[i] = fmaf(fmaf(qbf, akq[kg][r], aq), bt16[i], sa[kg][r]);             \
            }                                                                           \
        }                                                                               \
        if (t_ == NQT - 1) { /* mask k >= N */                                          \
            _Pragma("unroll") for (int kg = 0; kg < 4; ++kg)                            \
                _Pragma("unroll") for (int r = 0; r < 4; ++r) {                         \
                    if (1024 + kg * 16 + g * 4 + r >= N_) s[kg * 4 + r] = -1e30f;       \
                }                                                                       \
        }                                                                               \
        /* defer-max online softmax: no cross-lane work in the common path */           \
        float lmax = s[0];                                                              \
        _Pragma("unroll") for (int i = 1; i < 16; ++i) lmax = fmaxf(lmax, s[i]);        \
        if (t_ == 0) {                                                                  \
            float mt = fmaxf(lmax, __shfl_xor(lmax, 16));                               \
            m = fmaxf(mt, __shfl_xor(mt, 32));                                          \
        } else if (!__all(lmax <= m + THR_)) {                                          \
            float mt = fmaxf(lmax, __shfl_xor(lmax, 16));                               \
            mt = fmaxf(mt, __shfl_xor(mt, 32));                                         \
            const float mnew = fmaxf(m, mt);                                            \
            const float cc = EX2(m - mnew);                                             \
            m = mnew;                                                                   \
            lsum *= cc;                                                                 \
            float cc4[4];                                                               \
            _Pragma("unroll") for (int r = 0; r < 4; ++r) cc4[r] = __shfl(cc, g * 4 + r); \
            _Pragma("unroll") for (int dg = 0; dg < 4; ++dg)                            \
                _Pragma("unroll") for (int r = 0; r < 4; ++r) o[dg][r] *= cc4[r];       \
        }                                                                               \
        float pv16[16];                                                                 \
        float ls0 = 0.f, ls1 = 0.f;                                                     \
        _Pragma("unroll") for (int i = 0; i < 16; i += 2) {                             \
            pv16[i] = EX2(s[i] - m);                                                    \
            pv16[i + 1] = EX2(s[i + 1] - m);                                            \
            ls0 += pv16[i];                                                             \
            ls1 += pv16[i + 1];                                                         \
        }                                                                               \
        lsum += ls0 + ls1;                                                              \
        /* P -> f16, XOR-swizzled per-wave LDS (no barrier: private region) */          \
        _Pragma("unroll") for (int kg = 0; kg < 4; ++kg) {                              \
            fp16x2 h0 = __builtin_amdgcn_cvt_pkrtz(pv16[kg * 4 + 0], pv16[kg * 4 + 1]); \
            fp16x2 h1 = __builtin_amdgcn_cvt_pkrtz(pv16[kg * 4 + 2], pv16[kg * 4 + 3]); \
            uint2 u = make_uint2(__builtin_bit_cast(uint32_t, h0),                      \
                                 __builtin_bit_cast(uint32_t, h1));                     \
            *(uint2*)(plw + lq * 128 + ((kg * 32 + g * 8) ^ pswz)) = u;                 \
        }                                                                               \
        /* PV: C[q][d] += P[q][k] V[k][d] */                                            \
        _Pragma("unroll") for (int kh = 0; kh < 2; ++kh) {                              \
            half8 pa = *(const half8*)(plw + lq * 128 + ((kh * 64 + g * 16) ^ pswz));   \
            _Pragma("unroll") for (int dg = 0; dg < 4; ++dg) {                          \
                o[dg] = __builtin_amdgcn_mfma_f32_16x16x32_f16(pa, vv[kh * 4 + dg],     \
                                                               o[dg], 0, 0, 0);        \
            }                                                                           \
        }                                                                               \
    }

#pragma unroll 1
    for (int tt = 0; tt < NQT - 1; tt += 2) {
        TILE_BODY(kA, kB, tt, 1)
        TILE_BODY(kB, kA, tt + 1, 1)
    }
    TILE_BODY(kA, kB, NQT - 1, 0)
#undef TILE_BODY

    lsum += __shfl_xor(lsum, 16);
    lsum += __shfl_xor(lsum, 32);
    const float linv = 1.f / lsum;
    float li4[4];
#pragma unroll
    for (int r = 0; r < 4; ++r) li4[r] = __shfl(linv, g * 4 + r);
#pragma unroll
    for (int dg = 0; dg < 4; ++dg) {
#pragma unroll
        for (int r = 0; r < 4; ++r) {
            const int qq = qt * 64 + w * 16 + g * 4 + r;
            if (qq < N_) OUT[base + (size_t)qq * D_ + dg * 16 + lq] = o[dg][r] * li4[r];
        }
    }
}

extern "C" void kernel_launch(void* const* d_in, const int* in_sizes, int n_in,
                              void* d_out, int out_size, void* d_ws, size_t ws_size,
                              hipStream_t stream) {
    const float* q = (const float*)d_in[0];
    const float* k = (const float*)d_in[1];
    const float* v = (const float*)d_in[2];
    const float* mu = (const float*)d_in[3];
    const float* w1 = (const float*)d_in[4];
    const float* b1 = (const float*)d_in[5];
    const float* w2 = (const float*)d_in[6];
    const float* gamma = (const float*)d_in[7];
    const float* rel = (const float*)d_in[8];
    // d_in[9] = idx_table: reconstructed analytically, never read.

    char* ws = (char*)d_ws;
    float* btT = (float*)(ws + BTT_OFF);
    float* akT = (float*)(ws + AKT_OFF);
    _Float16* Kf = (_Float16*)(ws + KF_OFF);
    _Float16* Vf = (_Float16*)(ws + VF_OFF);

    prep<<<NBLK + (TBL_ + 255) / 256, 256, 0, stream>>>(k, v, mu, gamma, rel, w1, b1, w2,
                                                        Kf, Vf, akT, btT);
    flex_attn<<<NBLK, 256, 0, stream>>>(q, Kf, Vf, mu, gamma, ws - 2048, akT, (float*)d_out);
}

// Round 7
// 76.281 us; speedup vs baseline: 1.0673x; 1.0673x over previous
//
#include <hip/hip_runtime.h>
#include <math.h>

#define B_ 4
#define H_ 12
#define N_ 1025
#define D_ 64
#define HID_ 32
#define TBL_ 3969            // (2*32-1)^2
#define NQT 17               // 64-row tiles in both q and k
#define NBLK (B_ * H_ * NQT) // 816, divisible by 8
#define LOG2E 1.44269504f
#define THR_ 12.0f           // defer-max threshold (log2 domain); p <= 2^12 fits f16

typedef _Float16 half8 __attribute__((ext_vector_type(8)));
typedef __fp16 fp16x2 __attribute__((ext_vector_type(2)));
typedef float f32x4 __attribute__((ext_vector_type(4)));

#if defined(__has_builtin)
#if __has_builtin(__builtin_amdgcn_exp2f)
#define EX2 __builtin_amdgcn_exp2f
#else
#define EX2 exp2f
#endif
#else
#define EX2 exp2f
#endif

// ws layout (bytes):
//   btT @ 0        : 12*3969*4 = 190512
//   akT @ 190512   : 48*1088*4 = 208896   (also the finite overrun pad for btT)
//   Kf  @ 399408   : 48*17*4096*2 = 6684672
//   Vf  @ 7084080  : 6684672              (end 13768752)
#define BTT_OFF 0
#define AKT_OFF 190512
#define KF_OFF 399408
#define VF_OFF 7084080

__device__ __forceinline__ void stage16(const _Float16* gsrc, _Float16* ldst) {
    __builtin_amdgcn_global_load_lds(
        (const __attribute__((address_space(1))) void*)gsrc,
        (__attribute__((address_space(3))) void*)ldst, 16, 0, 0);
}

// ---------------- prep: K/V -> f16 fragment-order tiles (V via LDS transpose),
// akT = sigmoid(gamma)*log2e*mu_k, btT = MLP bias table (per-head transposed)
__global__ __launch_bounds__(256) void prep(
    const float* __restrict__ K, const float* __restrict__ V,
    const float* __restrict__ MU, const float* __restrict__ GAMMA,
    const float* __restrict__ rel, const float* __restrict__ w1,
    const float* __restrict__ b1, const float* __restrict__ w2,
    _Float16* __restrict__ Kf, _Float16* __restrict__ Vf,
    float* __restrict__ akT, float* __restrict__ btT) {
    const int bid = blockIdx.x;
    const int tid = threadIdx.x;
    if (bid < NBLK) {
        __shared__ float Vls[64 * 65];  // [d][k], pad 65 (2-way banks max)
        const int bh = bid / NQT, kt = bid % NQT;
        const size_t base = (size_t)bh * (N_ * D_);
        const int k0 = kt * 64;
        const int lane = tid & 63, lq = lane & 15, g = lane >> 4;
        const int fbh = tid >> 6;
        const size_t tb = (size_t)(bh * NQT + kt) * 4096;
        // ---- issue K fragment loads first (consumed after the barrier)
        float4 kld[2][2];
#pragma unroll
        for (int x = 0; x < 2; ++x) {
            const int fb = fbh + x * 4;
            const int row = k0 + (fb >> 1) * 16 + lq;
            const int col = (fb & 1) * 32 + g * 8;
            kld[x][0] = make_float4(0, 0, 0, 0);
            kld[x][1] = kld[x][0];
            if (row < N_) {
                const float4* p = (const float4*)(K + base + (size_t)row * D_ + col);
                kld[x][0] = p[0];
                kld[x][1] = p[1];
            }
        }
        // ---- V rows: coalesced global read -> transposed LDS scatter
#pragma unroll
        for (int it = 0; it < 4; ++it) {
            const int idx = it * 256 + tid;
            const int kr = idx >> 4, c4 = (idx & 15) << 2;
            const int kg = k0 + kr;
            float4 v4 = make_float4(0, 0, 0, 0);
            if (kg < N_) v4 = *(const float4*)(V + base + (size_t)kg * D_ + c4);
            Vls[(c4 + 0) * 65 + kr] = v4.x;
            Vls[(c4 + 1) * 65 + kr] = v4.y;
            Vls[(c4 + 2) * 65 + kr] = v4.z;
            Vls[(c4 + 3) * 65 + kr] = v4.w;
        }
        __syncthreads();
#pragma unroll
        for (int x = 0; x < 2; ++x) {
            const int fb = fbh + x * 4;
            {   // V fragment fb = kh*4+dg from LDS
                const int kh = fb >> 2, dg = fb & 3;
                const float* vp = &Vls[(dg * 16 + lq) * 65 + kh * 32 + g * 8];
                half8 v8;
#pragma unroll
                for (int j = 0; j < 8; ++j) v8[j] = (_Float16)vp[j];
                *(half8*)&Vf[tb + fb * 512 + lane * 8] = v8;
            }
            {   // K fragment fb = kg2*2+dh from the early loads
                half8 k8;
                float4 a = kld[x][0], b = kld[x][1];
                k8[0] = (_Float16)a.x; k8[1] = (_Float16)a.y;
                k8[2] = (_Float16)a.z; k8[3] = (_Float16)a.w;
                k8[4] = (_Float16)b.x; k8[5] = (_Float16)b.y;
                k8[6] = (_Float16)b.z; k8[7] = (_Float16)b.w;
                *(half8*)&Kf[tb + fb * 512 + lane * 8] = k8;
            }
        }
        if (tid < 64) {
            const int kk = k0 + tid;
            const int h = bh % H_;
            const float sgl = LOG2E / (1.f + __expf(-GAMMA[h]));
            float a = 0.f;
            if (kk >= 1 && kk < N_) a = sgl * MU[((size_t)bh * 2 + 1) * N_ + kk];
            akT[bh * 1088 + kk] = a;
        }
    } else {
        const int i = (bid - NBLK) * 256 + tid;
        if (i < TBL_) {
            const float x0 = rel[2 * i + 0], x1 = rel[2 * i + 1];
            float acc[H_];
#pragma unroll
            for (int h = 0; h < H_; ++h) acc[h] = 0.f;
#pragma unroll
            for (int j = 0; j < HID_; ++j) {
                float t = fmaf(x0, w1[j], fmaf(x1, w1[HID_ + j], b1[j]));
                float gl = 0.5f * t * (1.f + erff(t * 0.7071067811865475f));  // exact gelu
#pragma unroll
                for (int h = 0; h < H_; ++h) acc[h] = fmaf(gl, w2[j * H_ + h], acc[h]);
            }
#pragma unroll
            for (int h = 0; h < H_; ++h) btT[h * TBL_ + i] = acc[h];
        }
    }
}

// ---------------- fused flash attention, f16 MFMA, triple-buffered DMA staging,
// raw s_barrier per tile (no vmcnt(0) drain): stage(t+2) issued per tile; the
// compiler's wait for the in-tile bias gathers (issued BEFORE the stage, pinned
// by sched_barrier) forces stage(t+1) complete while stage(t+2) stays in flight.
__global__ __launch_bounds__(256, 2) void flex_attn(
    const float* __restrict__ Q, const _Float16* __restrict__ Kf,
    const _Float16* __restrict__ Vf, const float* __restrict__ MU,
    const float* __restrict__ GAMMA, const char* __restrict__ btb,  // ws - 2048
    const float* __restrict__ akT, float* __restrict__ OUT) {
    __shared__ __align__(16) _Float16 Ks[3][4096];
    __shared__ __align__(16) _Float16 Vs[3][4096];
    __shared__ __align__(16) _Float16 Pl[4][1024];  // per-wave P tile, XOR-swizzled

    const int bid = blockIdx.x;
    const int swz0 = (bid & 7) * (NBLK / 8) + (bid >> 3);  // bijective XCD swizzle
    const int bh = swz0 / NQT;
    const int qt = swz0 % NQT;
    const int h = bh % H_;
    const int tid = threadIdx.x;
    const int w = tid >> 6;
    const int lane = tid & 63;
    const int lq = lane & 15;
    const int g = lane >> 4;

    const size_t base = (size_t)bh * (N_ * D_);
    const float sg = LOG2E / (1.f + __expf(-GAMMA[h]));

    const int qrow = qt * 64 + w * 16 + lq;
    const bool qv = qrow < N_;

    // Q fragment (B-operand of swapped QK^T), scale = log2e/sqrt(64)
    half8 qf[2];
#pragma unroll
    for (int dh = 0; dh < 2; ++dh) {
        float4 t0 = make_float4(0, 0, 0, 0), t1 = t0;
        if (qv) {
            const float4* qp = (const float4*)(Q + base + (size_t)qrow * D_ + dh * 32 + g * 8);
            t0 = qp[0]; t1 = qp[1];
        }
        const float qs = 0.125f * LOG2E;
        half8 q8;
        q8[0] = (_Float16)(t0.x * qs); q8[1] = (_Float16)(t0.y * qs);
        q8[2] = (_Float16)(t0.z * qs); q8[3] = (_Float16)(t0.w * qs);
        q8[4] = (_Float16)(t1.x * qs); q8[5] = (_Float16)(t1.y * qs);
        q8[6] = (_Float16)(t1.z * qs); q8[7] = (_Float16)(t1.w * qs);
        qf[dh] = q8;
    }

    const bool qb = qv && (qrow >= 1);
    const float qbf = qb ? 1.f : 0.f;
    float aq = 0.f;
    int cq = 0;
    if (qb) {
        const int pq = qrow - 1;
        cq = (pq >> 5) * 63 + (pq & 31);
        aq = sg * MU[(size_t)bh * 2 * N_ + qrow];  // sg*log2e*mu_q
    }
    // bias gather byte offsets vs btb = ws-2048: off = (h*TBL + cq + 1984 - ck)*4 + 2048
    // per-tile recurrence: ck += 126 exactly  =>  off -= 504
    int boffs[16];
#pragma unroll
    for (int kg = 0; kg < 4; ++kg) {
#pragma unroll
        for (int r = 0; r < 4; ++r) {
            const int pk = kg * 16 + g * 4 + r - 1;       // tile 0
            const int ck = (pk >> 5) * 63 + (pk & 31);    // arith shift: ck(-1) = -32
            boffs[kg * 4 + r] = (h * TBL_ + cq + 1984 - ck) * 4 + 2048;
        }
    }
    const float* akb = akT + bh * 1088;
    const _Float16* kfb = Kf + (size_t)bh * NQT * 4096;
    const _Float16* vfb = Vf + (size_t)bh * NQT * 4096;

    f32x4 o[4];
    const f32x4 zz = {0.f, 0.f, 0.f, 0.f};
#pragma unroll
    for (int dg = 0; dg < 4; ++dg) o[dg] = zz;
    float m = 0.f, lsum = 0.f;

    const int pswz = (lq & 7) << 4;
    char* plw = (char*)&Pl[w][0];

    // prologue: stage tiles 0 and 1; wait only for tile 0 (vmcnt(4))
#pragma unroll
    for (int t0 = 0; t0 < 2; ++t0) {
        const _Float16* kp = kfb + (size_t)t0 * 4096;
        const _Float16* vp = vfb + (size_t)t0 * 4096;
        stage16(kp + (2 * w + 0) * 512 + lane * 8, &Ks[t0][(2 * w + 0) * 512]);
        stage16(kp + (2 * w + 1) * 512 + lane * 8, &Ks[t0][(2 * w + 1) * 512]);
        stage16(vp + (2 * w + 0) * 512 + lane * 8, &Vs[t0][(2 * w + 0) * 512]);
        stage16(vp + (2 * w + 1) * 512 + lane * 8, &Vs[t0][(2 * w + 1) * 512]);
    }
    asm volatile("s_waitcnt vmcnt(4)" ::: "memory");
    __builtin_amdgcn_sched_barrier(0);
    __builtin_amdgcn_s_barrier();

    int cur = 0, stg = 2;
#pragma unroll 1
    for (int t = 0; t < NQT; ++t) {
        const int kt0 = t * 64;

        // ---- bias gathers + gate k-terms: issued FIRST (FIFO position matters)
        float bt16[16];
#pragma unroll
        for (int i = 0; i < 16; ++i) {
            int off = boffs[i];
            off = off < 2048 ? 2048 : off;
            bt16[i] = *(const float*)(btb + (uint32_t)off);
            boffs[i] -= 504;
        }
        f32x4 akq[4];
#pragma unroll
        for (int kg = 0; kg < 4; ++kg)
            akq[kg] = *(const f32x4*)(akb + kt0 + kg * 16 + g * 4);
        __builtin_amdgcn_sched_barrier(0);  // pin: bias/akq before the stage below

        // ---- stage tile t+2 (stays in flight across the barrier; the bias wait
        //      above it in the FIFO only forces tile t+1's chunks complete)
        if (t + 2 < NQT) {
            const _Float16* kn = kfb + (size_t)(t + 2) * 4096;
            const _Float16* vn = vfb + (size_t)(t + 2) * 4096;
            stage16(kn + (2 * w + 0) * 512 + lane * 8, &Ks[stg][(2 * w + 0) * 512]);
            stage16(kn + (2 * w + 1) * 512 + lane * 8, &Ks[stg][(2 * w + 1) * 512]);
            stage16(vn + (2 * w + 0) * 512 + lane * 8, &Vs[stg][(2 * w + 0) * 512]);
            stage16(vn + (2 * w + 1) * 512 + lane * 8, &Vs[stg][(2 * w + 1) * 512]);
        }

        // ---- QK^T (swapped): C[k][q]; A-frags contiguous-by-lane (conflict-free)
        const _Float16* ksl = &Ks[cur][lane * 8];
        f32x4 sa[4];
#pragma unroll
        for (int kg = 0; kg < 4; ++kg) {
            half8 a0 = *(const half8*)(ksl + (2 * kg + 0) * 512);
            half8 a1 = *(const half8*)(ksl + (2 * kg + 1) * 512);
            f32x4 z = zz;
            z = __builtin_amdgcn_mfma_f32_16x16x32_f16(a0, qf[0], z, 0, 0, 0);
            z = __builtin_amdgcn_mfma_f32_16x16x32_f16(a1, qf[1], z, 0, 0, 0);
            sa[kg] = z;
        }

        // ---- scores (log2 domain): s = sa + (qbf*ak + aq)*bt
        if (t == 0 && g == 0) bt16[0] = 0.f;  // k=0 column has no bias
        float s[16];
#pragma unroll
        for (int kg = 0; kg < 4; ++kg) {
#pragma unroll
            for (int r = 0; r < 4; ++r) {
                const int i = kg * 4 + r;
                s[i] = fmaf(fmaf(qbf, akq[kg][r], aq), bt16[i], sa[kg][r]);
            }
        }
        if (t == NQT - 1) {  // mask k >= N
#pragma unroll
            for (int kg = 0; kg < 4; ++kg)
#pragma unroll
                for (int r = 0; r < 4; ++r) {
                    const int i = kg * 4 + r;
                    if (1024 + kg * 16 + g * 4 + r >= N_) s[i] = -1e30f;
                }
        }

        // ---- defer-max online softmax: no cross-lane work in the common path
        float lmax = s[0];
#pragma unroll
        for (int i = 1; i < 16; ++i) lmax = fmaxf(lmax, s[i]);
        if (t == 0) {
            float mt = fmaxf(lmax, __shfl_xor(lmax, 16));
            m = fmaxf(mt, __shfl_xor(mt, 32));
        } else if (!__all(lmax <= m + THR_)) {
            float mt = fmaxf(lmax, __shfl_xor(lmax, 16));
            mt = fmaxf(mt, __shfl_xor(mt, 32));
            const float mnew = fmaxf(m, mt);
            const float cc = EX2(m - mnew);
            m = mnew;
            lsum *= cc;
            float cc4[4];
#pragma unroll
            for (int r = 0; r < 4; ++r) cc4[r] = __shfl(cc, g * 4 + r);
#pragma unroll
            for (int dg = 0; dg < 4; ++dg)
#pragma unroll
                for (int r = 0; r < 4; ++r) o[dg][r] *= cc4[r];
        }
        float pv16[16];
        float ls0 = 0.f, ls1 = 0.f;
#pragma unroll
        for (int i = 0; i < 16; i += 2) {
            pv16[i] = EX2(s[i] - m);
            pv16[i + 1] = EX2(s[i + 1] - m);
            ls0 += pv16[i];
            ls1 += pv16[i + 1];
        }
        lsum += ls0 + ls1;

        // ---- P -> f16, XOR-swizzled per-wave LDS (wave-private region)
#pragma unroll
        for (int kg = 0; kg < 4; ++kg) {
            fp16x2 h0 = __builtin_amdgcn_cvt_pkrtz(pv16[kg * 4 + 0], pv16[kg * 4 + 1]);
            fp16x2 h1 = __builtin_amdgcn_cvt_pkrtz(pv16[kg * 4 + 2], pv16[kg * 4 + 3]);
            uint2 u = make_uint2(__builtin_bit_cast(uint32_t, h0),
                                 __builtin_bit_cast(uint32_t, h1));
            *(uint2*)(plw + lq * 128 + ((kg * 32 + g * 8) ^ pswz)) = u;
        }

        // ---- PV: C[q][d] += P[q][k] V[k][d]
#pragma unroll
        for (int kh = 0; kh < 2; ++kh) {
            half8 pa = *(const half8*)(plw + lq * 128 + ((kh * 64 + g * 16) ^ pswz));
#pragma unroll
            for (int dg = 0; dg < 4; ++dg) {
                half8 vb8 = *(const half8*)&Vs[cur][(kh * 4 + dg) * 512 + lane * 8];
                o[dg] = __builtin_amdgcn_mfma_f32_16x16x32_f16(pa, vb8, o[dg], 0, 0, 0);
            }
        }
        // raw barrier: all waves done reading buf `cur`; every wave's stage(t+1)
        // already completed (forced by its own bias wait) => next tile is ready.
        __builtin_amdgcn_s_barrier();
        cur = (cur == 2) ? 0 : cur + 1;
        stg = (stg == 2) ? 0 : stg + 1;
    }

    lsum += __shfl_xor(lsum, 16);
    lsum += __shfl_xor(lsum, 32);
    const float linv = 1.f / lsum;
    float li4[4];
#pragma unroll
    for (int r = 0; r < 4; ++r) li4[r] = __shfl(linv, g * 4 + r);
#pragma unroll
    for (int dg = 0; dg < 4; ++dg) {
#pragma unroll
        for (int r = 0; r < 4; ++r) {
            const int qq = qt * 64 + w * 16 + g * 4 + r;
            if (qq < N_) OUT[base + (size_t)qq * D_ + dg * 16 + lq] = o[dg][r] * li4[r];
        }
    }
}

extern "C" void kernel_launch(void* const* d_in, const int* in_sizes, int n_in,
                              void* d_out, int out_size, void* d_ws, size_t ws_size,
                              hipStream_t stream) {
    const float* q = (const float*)d_in[0];
    const float* k = (const float*)d_in[1];
    const float* v = (const float*)d_in[2];
    const float* mu = (const float*)d_in[3];
    const float* w1 = (const float*)d_in[4];
    const float* b1 = (const float*)d_in[5];
    const float* w2 = (const float*)d_in[6];
    const float* gamma = (const float*)d_in[7];
    const float* rel = (const float*)d_in[8];
    // d_in[9] = idx_table: reconstructed analytically, never read.

    char* ws = (char*)d_ws;
    float* btT = (float*)(ws + BTT_OFF);
    float* akT = (float*)(ws + AKT_OFF);
    _Float16* Kf = (_Float16*)(ws + KF_OFF);
    _Float16* Vf = (_Float16*)(ws + VF_OFF);

    prep<<<NBLK + (TBL_ + 255) / 256, 256, 0, stream>>>(k, v, mu, gamma, rel, w1, b1, w2,
                                                        Kf, Vf, akT, btT);
    flex_attn<<<NBLK, 256, 0, stream>>>(q, Kf, Vf, mu, gamma, ws - 2048, akT, (float*)d_out);
}

// Round 8
// 73.878 us; speedup vs baseline: 1.1020x; 1.0325x over previous
//
#include <hip/hip_runtime.h>
#include <math.h>

#define B_ 4
#define H_ 12
#define N_ 1025
#define D_ 64
#define HID_ 32
#define TBL_ 3969            // (2*32-1)^2
#define NQT 17               // 64-row tiles in both q and k
#define NBLK (B_ * H_ * NQT) // 816, divisible by 8
#define LOG2E 1.44269504f
#define THR_ 12.0f           // defer-max threshold (log2 domain); p <= 2^12 fits f16

typedef _Float16 half8 __attribute__((ext_vector_type(8)));
typedef __fp16 fp16x2 __attribute__((ext_vector_type(2)));
typedef float f32x4 __attribute__((ext_vector_type(4)));

#if defined(__has_builtin)
#if __has_builtin(__builtin_amdgcn_exp2f)
#define EX2 __builtin_amdgcn_exp2f
#else
#define EX2 exp2f
#endif
#else
#define EX2 exp2f
#endif

// ws layout (bytes):
//   btT @ 0        : 12*3969*4 = 190512
//   akT @ 190512   : 48*1088*4 = 208896   (also the finite overrun pad for btT)
//   Kf  @ 399408   : 48*17*4096*2 = 6684672
//   Vf  @ 7084080  : 6684672              (end 13768752)
#define BTT_OFF 0
#define AKT_OFF 190512
#define KF_OFF 399408
#define VF_OFF 7084080

__device__ __forceinline__ void stage16(const _Float16* gsrc, _Float16* ldst) {
    __builtin_amdgcn_global_load_lds(
        (const __attribute__((address_space(1))) void*)gsrc,
        (__attribute__((address_space(3))) void*)ldst, 16, 0, 0);
}

__device__ __forceinline__ uint32_t pk2(float a, float b) {
    fp16x2 t = __builtin_amdgcn_cvt_pkrtz(a, b);
    return __builtin_bit_cast(uint32_t, t);
}

// ---------------- prep: K/V -> f16 fragment-order tiles, akT, btT (MLP table)
// V transpose via packed f16 row-pairs: u32 = (row 2p, row 2p+1), LDS stride 36
// so the fragment read is one aligned uint4 (8 consecutive k at fixed d).
__global__ __launch_bounds__(256) void prep(
    const float* __restrict__ K, const float* __restrict__ V,
    const float* __restrict__ MU, const float* __restrict__ GAMMA,
    const float* __restrict__ rel, const float* __restrict__ w1,
    const float* __restrict__ b1, const float* __restrict__ w2,
    _Float16* __restrict__ Kf, _Float16* __restrict__ Vf,
    float* __restrict__ akT, float* __restrict__ btT) {
    const int bid = blockIdx.x;
    const int tid = threadIdx.x;
    if (bid < NBLK) {
        __shared__ uint32_t VlsU[64 * 36];  // [d][kpair] packed f16 pairs
        const int bh = bid / NQT, kt = bid % NQT;
        const size_t base = (size_t)bh * (N_ * D_);
        const int k0 = kt * 64;
        const int lane = tid & 63, lq = lane & 15, g = lane >> 4;
        const int fbh = tid >> 6;
        const size_t tb = (size_t)(bh * NQT + kt) * 4096;
        // ---- K fragment loads issued first (consumed after the barrier)
        float4 kld[2][2];
#pragma unroll
        for (int x = 0; x < 2; ++x) {
            const int fb = fbh + x * 4;
            const int row = k0 + (fb >> 1) * 16 + lq;
            const int col = (fb & 1) * 32 + g * 8;
            kld[x][0] = make_float4(0, 0, 0, 0);
            kld[x][1] = kld[x][0];
            if (row < N_) {
                const float4* p = (const float4*)(K + base + (size_t)row * D_ + col);
                kld[x][0] = p[0];
                kld[x][1] = p[1];
            }
        }
        // ---- V: read row pairs, pack to f16 pairs, transposed LDS store
#pragma unroll
        for (int it = 0; it < 2; ++it) {
            const int idx = it * 256 + tid;   // 0..511
            const int p = idx >> 4;           // k-pair 0..31
            const int c4 = (idx & 15) << 2;   // d column
            const int r0 = k0 + 2 * p;
            float4 a = make_float4(0, 0, 0, 0), b = a;
            if (r0 < N_) a = *(const float4*)(V + base + (size_t)r0 * D_ + c4);
            if (r0 + 1 < N_) b = *(const float4*)(V + base + (size_t)(r0 + 1) * D_ + c4);
            VlsU[(c4 + 0) * 36 + p] = pk2(a.x, b.x);
            VlsU[(c4 + 1) * 36 + p] = pk2(a.y, b.y);
            VlsU[(c4 + 2) * 36 + p] = pk2(a.z, b.z);
            VlsU[(c4 + 3) * 36 + p] = pk2(a.w, b.w);
        }
        __syncthreads();
#pragma unroll
        for (int x = 0; x < 2; ++x) {
            const int fb = fbh + x * 4;
            {   // V fragment fb = kh*4+dg: one aligned uint4 from LDS
                const int kh = fb >> 2, dg = fb & 3;
                uint4 u = *(const uint4*)&VlsU[(dg * 16 + lq) * 36 + kh * 16 + g * 4];
                *(uint4*)&Vf[tb + fb * 512 + lane * 8] = u;
            }
            {   // K fragment fb = kg2*2+dh from the early loads
                half8 k8;
                float4 a = kld[x][0], b = kld[x][1];
                k8[0] = (_Float16)a.x; k8[1] = (_Float16)a.y;
                k8[2] = (_Float16)a.z; k8[3] = (_Float16)a.w;
                k8[4] = (_Float16)b.x; k8[5] = (_Float16)b.y;
                k8[6] = (_Float16)b.z; k8[7] = (_Float16)b.w;
                *(half8*)&Kf[tb + fb * 512 + lane * 8] = k8;
            }
        }
        if (tid < 64) {
            const int kk = k0 + tid;
            const int h = bh % H_;
            const float sgl = LOG2E / (1.f + __expf(-GAMMA[h]));
            float a = 0.f;
            if (kk >= 1 && kk < N_) a = sgl * MU[((size_t)bh * 2 + 1) * N_ + kk];
            akT[bh * 1088 + kk] = a;
        }
    } else {
        const int i = (bid - NBLK) * 256 + tid;
        if (i < TBL_) {
            const float x0 = rel[2 * i + 0], x1 = rel[2 * i + 1];
            float acc[H_];
#pragma unroll
            for (int h = 0; h < H_; ++h) acc[h] = 0.f;
#pragma unroll
            for (int j = 0; j < HID_; ++j) {
                float t = fmaf(x0, w1[j], fmaf(x1, w1[HID_ + j], b1[j]));
                float gl = 0.5f * t * (1.f + erff(t * 0.7071067811865475f));  // exact gelu
#pragma unroll
                for (int h = 0; h < H_; ++h) acc[h] = fmaf(gl, w2[j * H_ + h], acc[h]);
            }
#pragma unroll
            for (int h = 0; h < H_; ++h) btT[h * TBL_ + i] = acc[h];
        }
    }
}

// ---------------- fused flash attention: 2 waves/block, 2 q-subtiles per wave
// (32 q-rows/wave) so K/V LDS reads amortize over 2x work; round-5 2-buffer
// DMA staging + __syncthreads skeleton (proven best).
__global__ __launch_bounds__(128, 2) void flex_attn(
    const float* __restrict__ Q, const _Float16* __restrict__ Kf,
    const _Float16* __restrict__ Vf, const float* __restrict__ MU,
    const float* __restrict__ GAMMA, const char* __restrict__ btb,  // ws - 2048
    const float* __restrict__ akT, float* __restrict__ OUT) {
    __shared__ __align__(16) _Float16 Ks[2][4096];
    __shared__ __align__(16) _Float16 Vs[2][4096];
    __shared__ __align__(16) _Float16 Pl[2][2][1024];  // [wave][sub][16q x 64k] swizzled

    const int bid = blockIdx.x;
    const int swz0 = (bid & 7) * (NBLK / 8) + (bid >> 3);  // bijective XCD swizzle
    const int bh = swz0 / NQT;
    const int qt = swz0 % NQT;
    const int h = bh % H_;
    const int tid = threadIdx.x;
    const int w = tid >> 6;      // 2 waves
    const int lane = tid & 63;
    const int lq = lane & 15;
    const int g = lane >> 4;

    const size_t base = (size_t)bh * (N_ * D_);
    const float sg = LOG2E / (1.f + __expf(-GAMMA[h]));

    const int qrow0 = qt * 64 + w * 32 + lq;
    const int qrow1 = qrow0 + 16;
    const bool qv0 = qrow0 < N_;
    const bool qv1 = qrow1 < N_;

    // Q fragments for both subtiles, scale = log2e/sqrt(64)
    half8 qf0[2], qf1[2];
#pragma unroll
    for (int sub = 0; sub < 2; ++sub) {
        const int qr = sub ? qrow1 : qrow0;
        const bool v = sub ? qv1 : qv0;
#pragma unroll
        for (int dh = 0; dh < 2; ++dh) {
            float4 t0 = make_float4(0, 0, 0, 0), t1 = t0;
            if (v) {
                const float4* qp = (const float4*)(Q + base + (size_t)qr * D_ + dh * 32 + g * 8);
                t0 = qp[0]; t1 = qp[1];
            }
            const float qs = 0.125f * LOG2E;
            half8 q8;
            q8[0] = (_Float16)(t0.x * qs); q8[1] = (_Float16)(t0.y * qs);
            q8[2] = (_Float16)(t0.z * qs); q8[3] = (_Float16)(t0.w * qs);
            q8[4] = (_Float16)(t1.x * qs); q8[5] = (_Float16)(t1.y * qs);
            q8[6] = (_Float16)(t1.z * qs); q8[7] = (_Float16)(t1.w * qs);
            if (sub) qf1[dh] = q8; else qf0[dh] = q8;
        }
    }

    const bool qb0 = qv0 && (qrow0 >= 1);
    const bool qb1 = qv1;  // qrow1 >= 16 always
    const float qbf0 = qb0 ? 1.f : 0.f;
    const float qbf1 = qb1 ? 1.f : 0.f;
    float aq0 = 0.f, aq1 = 0.f;
    int cq0 = 0, cq1 = 0;
    if (qb0) {
        const int pq = qrow0 - 1;
        cq0 = (pq >> 5) * 63 + (pq & 31);
        aq0 = sg * MU[(size_t)bh * 2 * N_ + qrow0];
    }
    if (qb1) {
        const int pq = qrow1 - 1;
        cq1 = (pq >> 5) * 63 + (pq & 31);
        aq1 = sg * MU[(size_t)bh * 2 * N_ + qrow1];
    }
    // bias byte offsets vs btb = ws-2048: off = (h*TBL + cq + 1984 - ck)*4 + 2048
    // tile recurrence: ck += 126 => off -= 504. Sub1 = sub0 + dB (linear in cq).
    int boffs[16];
#pragma unroll
    for (int kg = 0; kg < 4; ++kg) {
#pragma unroll
        for (int r = 0; r < 4; ++r) {
            const int pk = kg * 16 + g * 4 + r - 1;       // tile 0
            const int ck = (pk >> 5) * 63 + (pk & 31);    // arith shift: ck(-1) = -32
            boffs[kg * 4 + r] = (h * TBL_ + cq0 + 1984 - ck) * 4 + 2048;
        }
    }
    const int dB = (cq1 - cq0) * 4;
    const float* akb = akT + bh * 1088;
    const _Float16* kfb = Kf + (size_t)bh * NQT * 4096;
    const _Float16* vfb = Vf + (size_t)bh * NQT * 4096;

    f32x4 o0[4], o1[4];
    const f32x4 zz = {0.f, 0.f, 0.f, 0.f};
#pragma unroll
    for (int dg = 0; dg < 4; ++dg) { o0[dg] = zz; o1[dg] = zz; }
    float m0 = 0.f, l0 = 0.f, m1 = 0.f, l1 = 0.f;

    const int pswz = (lq & 7) << 4;
    char* plw0 = (char*)&Pl[w][0][0];
    char* plw1 = (char*)&Pl[w][1][0];

    // prologue: stage tile 0 (each wave: 4 K-chunks + 4 V-chunks of 1KB)
#pragma unroll
    for (int c = 0; c < 4; ++c) {
        stage16(kfb + (4 * w + c) * 512 + lane * 8, &Ks[0][(4 * w + c) * 512]);
        stage16(vfb + (4 * w + c) * 512 + lane * 8, &Vs[0][(4 * w + c) * 512]);
    }
    __syncthreads();

#pragma unroll 1
    for (int t = 0; t < NQT; ++t) {
        const int buf = t & 1;
        const int kt0 = t * 64;

        // ---- bias gathers (both subtiles) + gate k-terms
        float btA[16], btB[16];
#pragma unroll
        for (int i = 0; i < 16; ++i) {
            int offA = boffs[i];
            int offB = offA + dB;
            offA = offA < 2048 ? 2048 : offA;
            offB = offB < 2048 ? 2048 : offB;
            btA[i] = *(const float*)(btb + (uint32_t)offA);
            btB[i] = *(const float*)(btb + (uint32_t)offB);
            boffs[i] -= 504;
        }
        f32x4 akq[4];
#pragma unroll
        for (int kg = 0; kg < 4; ++kg)
            akq[kg] = *(const f32x4*)(akb + kt0 + kg * 16 + g * 4);

        // ---- stage next tile into the other buffer
        if (t + 1 < NQT) {
            const _Float16* kn = kfb + (size_t)(t + 1) * 4096;
            const _Float16* vn = vfb + (size_t)(t + 1) * 4096;
#pragma unroll
            for (int c = 0; c < 4; ++c) {
                stage16(kn + (4 * w + c) * 512 + lane * 8, &Ks[buf ^ 1][(4 * w + c) * 512]);
                stage16(vn + (4 * w + c) * 512 + lane * 8, &Vs[buf ^ 1][(4 * w + c) * 512]);
            }
        }

        // ---- QK^T (swapped): C[k][q]; K-frags read ONCE, used by both subtiles
        const _Float16* ksl = &Ks[buf][lane * 8];
        f32x4 sa0[4], sa1[4];
#pragma unroll
        for (int kg = 0; kg < 4; ++kg) {
            half8 a0 = *(const half8*)(ksl + (2 * kg + 0) * 512);
            half8 a1 = *(const half8*)(ksl + (2 * kg + 1) * 512);
            f32x4 z0 = zz, z1 = zz;
            z0 = __builtin_amdgcn_mfma_f32_16x16x32_f16(a0, qf0[0], z0, 0, 0, 0);
            z1 = __builtin_amdgcn_mfma_f32_16x16x32_f16(a0, qf1[0], z1, 0, 0, 0);
            z0 = __builtin_amdgcn_mfma_f32_16x16x32_f16(a1, qf0[1], z0, 0, 0, 0);
            z1 = __builtin_amdgcn_mfma_f32_16x16x32_f16(a1, qf1[1], z1, 0, 0, 0);
            sa0[kg] = z0;
            sa1[kg] = z1;
        }

        if (t == 0 && g == 0) { btA[0] = 0.f; btB[0] = 0.f; }  // k=0: no bias

        // ---- per-subtile: scores + defer-max softmax + P write
#define SOFTMAX_SUB(SA, BT, QBF, AQ, MM, LL, OO, PLW)                                  \
    {                                                                                  \
        float s[16];                                                                   \
        _Pragma("unroll") for (int kg = 0; kg < 4; ++kg) {                             \
            _Pragma("unroll") for (int r = 0; r < 4; ++r) {                            \
                const int i = kg * 4 + r;                                              \
                s[i] = fmaf(fmaf(QBF, akq[kg][r], AQ), BT[i], SA[kg][r]);              \
            }                                                                          \
        }                                                                              \
        if (t == NQT - 1) {                                                            \
            _Pragma("unroll") for (int kg = 0; kg < 4; ++kg)                           \
                _Pragma("unroll") for (int r = 0; r < 4; ++r) {                        \
                    if (1024 + kg * 16 + g * 4 + r >= N_) s[kg * 4 + r] = -1e30f;      \
                }                                                                      \
        }                                                                              \
        float lmax = s[0];                                                             \
        _Pragma("unroll") for (int i = 1; i < 16; ++i) lmax = fmaxf(lmax, s[i]);       \
        if (t == 0) {                                                                  \
            float mt = fmaxf(lmax, __shfl_xor(lmax, 16));                              \
            MM = fmaxf(mt, __shfl_xor(mt, 32));                                        \
        } else if (!__all(lmax <= MM + THR_)) {                                        \
            float mt = fmaxf(lmax, __shfl_xor(lmax, 16));                              \
            mt = fmaxf(mt, __shfl_xor(mt, 32));                                        \
            const float mnew = fmaxf(MM, mt);                                          \
            const float cc = EX2(MM - mnew);                                           \
            MM = mnew;                                                                 \
            LL *= cc;                                                                  \
            float cc4[4];                                                              \
            _Pragma("unroll") for (int r = 0; r < 4; ++r) cc4[r] = __shfl(cc, g * 4 + r); \
            _Pragma("unroll") for (int dg = 0; dg < 4; ++dg)                           \
                _Pragma("unroll") for (int r = 0; r < 4; ++r) OO[dg][r] *= cc4[r];     \
        }                                                                              \
        float pv16[16];                                                                \
        float ls0 = 0.f, ls1 = 0.f;                                                    \
        _Pragma("unroll") for (int i = 0; i < 16; i += 2) {                            \
            pv16[i] = EX2(s[i] - MM);                                                  \
            pv16[i + 1] = EX2(s[i + 1] - MM);                                          \
            ls0 += pv16[i];                                                            \
            ls1 += pv16[i + 1];                                                        \
        }                                                                              \
        LL += ls0 + ls1;                                                               \
        _Pragma("unroll") for (int kg = 0; kg < 4; ++kg) {                             \
            uint2 u = make_uint2(pk2(pv16[kg * 4 + 0], pv16[kg * 4 + 1]),              \
                                 pk2(pv16[kg * 4 + 2], pv16[kg * 4 + 3]));             \
            *(uint2*)(PLW + lq * 128 + ((kg * 32 + g * 8) ^ pswz)) = u;                \
        }                                                                              \
    }

        SOFTMAX_SUB(sa0, btA, qbf0, aq0, m0, l0, o0, plw0)
        SOFTMAX_SUB(sa1, btB, qbf1, aq1, m1, l1, o1, plw1)
#undef SOFTMAX_SUB

        // ---- PV: V-frags read ONCE, used by both subtiles
#pragma unroll
        for (int kh = 0; kh < 2; ++kh) {
            half8 pa0 = *(const half8*)(plw0 + lq * 128 + ((kh * 64 + g * 16) ^ pswz));
            half8 pa1 = *(const half8*)(plw1 + lq * 128 + ((kh * 64 + g * 16) ^ pswz));
#pragma unroll
            for (int dg = 0; dg < 4; ++dg) {
                half8 vb8 = *(const half8*)&Vs[buf][(kh * 4 + dg) * 512 + lane * 8];
                o0[dg] = __builtin_amdgcn_mfma_f32_16x16x32_f16(pa0, vb8, o0[dg], 0, 0, 0);
                o1[dg] = __builtin_amdgcn_mfma_f32_16x16x32_f16(pa1, vb8, o1[dg], 0, 0, 0);
            }
        }
        __syncthreads();
    }

    // ---- epilogue, per subtile
    l0 += __shfl_xor(l0, 16); l0 += __shfl_xor(l0, 32);
    l1 += __shfl_xor(l1, 16); l1 += __shfl_xor(l1, 32);
    const float li0 = 1.f / l0;
    const float li1 = 1.f / l1;
    float li4a[4], li4b[4];
#pragma unroll
    for (int r = 0; r < 4; ++r) {
        li4a[r] = __shfl(li0, g * 4 + r);
        li4b[r] = __shfl(li1, g * 4 + r);
    }
#pragma unroll
    for (int dg = 0; dg < 4; ++dg) {
#pragma unroll
        for (int r = 0; r < 4; ++r) {
            const int qq0 = qt * 64 + w * 32 + g * 4 + r;
            if (qq0 < N_) OUT[base + (size_t)qq0 * D_ + dg * 16 + lq] = o0[dg][r] * li4a[r];
            const int qq1 = qq0 + 16;
            if (qq1 < N_) OUT[base + (size_t)qq1 * D_ + dg * 16 + lq] = o1[dg][r] * li4b[r];
        }
    }
}

extern "C" void kernel_launch(void* const* d_in, const int* in_sizes, int n_in,
                              void* d_out, int out_size, void* d_ws, size_t ws_size,
                              hipStream_t stream) {
    const float* q = (const float*)d_in[0];
    const float* k = (const float*)d_in[1];
    const float* v = (const float*)d_in[2];
    const float* mu = (const float*)d_in[3];
    const float* w1 = (const float*)d_in[4];
    const float* b1 = (const float*)d_in[5];
    const float* w2 = (const float*)d_in[6];
    const float* gamma = (const float*)d_in[7];
    const float* rel = (const float*)d_in[8];
    // d_in[9] = idx_table: reconstructed analytically, never read.

    char* ws = (char*)d_ws;
    float* btT = (float*)(ws + BTT_OFF);
    float* akT = (float*)(ws + AKT_OFF);
    _Float16* Kf = (_Float16*)(ws + KF_OFF);
    _Float16* Vf = (_Float16*)(ws + VF_OFF);

    prep<<<NBLK + (TBL_ + 255) / 256, 256, 0, stream>>>(k, v, mu, gamma, rel, w1, b1, w2,
                                                        Kf, Vf, akT, btT);
    flex_attn<<<NBLK, 128, 0, stream>>>(q, Kf, Vf, mu, gamma, ws - 2048, akT, (float*)d_out);
}